// Round 5
// baseline (427.134 us; speedup 1.0000x reference)
//
#include <hip/hip_runtime.h>
#include <math.h>

// N=64, C=256, T=64, V=25 graph-ODE, 4 fused blocks. bf16 MFMA 32x32x16.
// R5: persistent fused kernel. 512 WGs x 512 thr; each WG owns 8 slabs (one n,
// one t-octet). Per wave: w o-tile fragments in REGISTERS (64 VGPR, reloaded
// per block, reused across 8 slabs -> w L2 traffic /8), residual in REGISTERS
// (C/D layout, packed bf16). One barrier per slab (double-buffered yT).
#define NN 64
#define CC 256
#define TT 64
#define VV 25

typedef __bf16 bf16;
typedef unsigned int u32;
typedef __attribute__((ext_vector_type(8)))  __bf16 bf16x8;
typedef __attribute__((ext_vector_type(4)))  __bf16 bf16x4;
typedef __attribute__((ext_vector_type(16))) float  f32x16;

#define RS 40    // scm row stride (bf16): 80 B, 16B-aligned, gcd(20dw,32)=4 spread
#define YS 264   // syT row stride (bf16): 528 B, 4dw-mod-32 spread

static __device__ __forceinline__ u32 pk2(float a, float b) {
    unsigned short ua = __builtin_bit_cast(unsigned short, (bf16)a);
    unsigned short ub = __builtin_bit_cast(unsigned short, (bf16)b);
    return (u32)ua | ((u32)ub << 16);
}
static __device__ __forceinline__ float uplo(u32 w) {
    return (float)__builtin_bit_cast(bf16, (unsigned short)(w & 0xffffu));
}
static __device__ __forceinline__ float uphi(u32 w) {
    return (float)__builtin_bit_cast(bf16, (unsigned short)(w >> 16));
}
static __device__ __forceinline__ bf16 us2bf(unsigned short u) {
    return __builtin_bit_cast(bf16, u);
}

// ---- pack four 256x256 fp32 w into bf16 MFMA A-fragment order ----
// wp[(((blk*8+ot)*16+k)*64 + lane)*8 + e] = w_blk[ot*32+(lane&31)][k*16+(lane>>5)*8+e]
__global__ void convert_w(const float* __restrict__ w1, const float* __restrict__ w2,
                          const float* __restrict__ w3, const float* __restrict__ w4,
                          bf16* __restrict__ wp) {
    const int gid = blockIdx.x * 256 + threadIdx.x;   // 0..32767
    const int e8  = gid * 8;
    const int blk = e8 >> 16;
    const int off = e8 & 65535;
    const int row = off >> 8;
    const int col = off & 255;
    const float* src = (blk == 0) ? w1 : (blk == 1) ? w2 : (blk == 2) ? w3 : w4;
    const float4 f0 = *(const float4*)(src + off);
    const float4 f1 = *(const float4*)(src + off + 4);
    bf16x8 o;
    o[0] = (bf16)f0.x; o[1] = (bf16)f0.y; o[2] = (bf16)f0.z; o[3] = (bf16)f0.w;
    o[4] = (bf16)f1.x; o[5] = (bf16)f1.y; o[6] = (bf16)f1.z; o[7] = (bf16)f1.w;
    const int ot = row >> 5, l31r = row & 31;
    const int k = col >> 4, lhc = (col >> 3) & 1;
    *(bf16x8*)(wp + ((size_t)(((blk * 8 + ot) * 16 + k) * 64) + lhc * 32 + l31r) * 8) = o;
}

#define MFMA(A, B, C) __builtin_amdgcn_mfma_f32_32x32x16_bf16(A, B, C, 0, 0, 0)

__global__ __launch_bounds__(512, 2) void ode_fused(
    const float* __restrict__ x, const float* __restrict__ Amat,
    const bf16* __restrict__ wp,
    const float* __restrict__ b1, const float* __restrict__ b2,
    const float* __restrict__ b3, const float* __restrict__ b4,
    float* __restrict__ out)
{
    __shared__ bf16  syT[2][32][YS];     // 33792 B, double-buffered y^T
    __shared__ bf16  scm[CC][RS];        // 20480 B, wave-private-by-tile c-major res
    __shared__ float sbias[4][CC];       // 4096 B
    __shared__ bf16  sAb[32][32];        // 2048 B, zero-padded A

    const int tid  = threadIdx.x;
    const int wv   = tid >> 6;          // 0..7 : o-tile / c-tile owner
    const int lane = tid & 63;
    const int lh   = lane >> 5;
    const int l31  = lane & 31;
    const int n    = blockIdx.x >> 3;
    const int t0   = (blockIdx.x & 7) * 8;

    // ---- stage biases + A ----
    if (tid < 256) { sbias[0][tid] = b1[tid]; sbias[1][tid] = b2[tid]; }
    else { const int c = tid - 256; sbias[2][c] = b3[c]; sbias[3][c] = b4[c]; }
    for (int i = tid; i < 1024; i += 512) {
        const int v = i >> 5, u = i & 31;
        sAb[v][u] = (v < VV && u < VV) ? (bf16)Amat[v * VV + u] : (bf16)0.f;
    }
    __syncthreads();

    // Phase-A B-fragments (constant all blocks): B[k=u][n=v] = A[v][u]
    const bf16x8 AB0 = *(const bf16x8*)&sAb[l31][lh * 8];
    const bf16x8 AB1 = *(const bf16x8*)&sAb[l31][16 + lh * 8];

    // ---- load x -> residual registers, C/D layout, packed bf16 ----
    // elem r of a slab: o = 32*wv + 4*lh + 2*(m&1) + 8*(m>>1) (+1 for hi half), v = l31
    u32 rp[8][8];
    {
        const int vq = (l31 < VV) ? l31 : VV - 1;   // clamp; junk lanes masked later
        const float* xb = x + ((size_t)n * CC * TT + t0) * VV + vq;
        #pragma unroll
        for (int s = 0; s < 8; ++s) {
            #pragma unroll
            for (int m = 0; m < 8; ++m) {
                const int o0 = 32 * wv + 4 * lh + 2 * (m & 1) + 8 * (m >> 1);
                const float f0 = xb[((size_t)o0 * TT + s) * VV];
                const float f1 = xb[((size_t)(o0 + 1) * TT + s) * VV];
                rp[s][m] = pk2(f0, f1);
            }
        }
    }

    for (int blk = 0; blk < 4; ++blk) {
        // ---- per-block: w fragments into registers (reused by all 8 slabs) ----
        bf16x8 wf[16];
        const bf16* wpb = wp + ((size_t)((blk * 8 + wv) * 16) * 64 + lane) * 8;
        #pragma unroll
        for (int k = 0; k < 16; ++k) wf[k] = *(const bf16x8*)(wpb + (size_t)k * 512);

        float bq[16];
        #pragma unroll
        for (int r = 0; r < 16; ++r)
            bq[r] = sbias[blk][32 * wv + (r & 3) + 8 * (r >> 2) + 4 * lh];

        #pragma unroll
        for (int s = 0; s < 8; ++s) {
            const int buf = s & 1;
            // ===== Phase A: y = res . A^T (own 32-row c-tile) =====
            #pragma unroll
            for (int m = 0; m < 8; ++m) {
                const u32 w = rp[s][m];
                const int c0 = 32 * wv + 4 * lh + 2 * (m & 1) + 8 * (m >> 1);
                scm[c0][l31]     = us2bf((unsigned short)(w & 0xffffu));
                scm[c0 + 1][l31] = us2bf((unsigned short)(w >> 16));
            }
            const bf16x8 af0 = *(const bf16x8*)&scm[32 * wv + l31][lh * 8];
            const bf16x8 af1 = *(const bf16x8*)&scm[32 * wv + l31][16 + lh * 8];
            f32x16 d = {};
            d = MFMA(af0, AB0, d);
            d = MFMA(af1, AB1, d);
            if (l31 < VV) {
                #pragma unroll
                for (int g = 0; g < 4; ++g) {
                    bf16x4 p;
                    p[0] = (bf16)d[4 * g];     p[1] = (bf16)d[4 * g + 1];
                    p[2] = (bf16)d[4 * g + 2]; p[3] = (bf16)d[4 * g + 3];
                    *(bf16x4*)&syT[buf][l31][32 * wv + 8 * g + 4 * lh] = p;
                }
            }
            __syncthreads();

            // ===== Phase G: z = W . y (w frags in regs; only LDS y reads) =====
            f32x16 acc0 = {}, acc1 = {};
            #pragma unroll
            for (int k = 0; k < 16; k += 2) {
                const bf16x8 y0 = *(const bf16x8*)&syT[buf][l31][k * 16 + lh * 8];
                const bf16x8 y1 = *(const bf16x8*)&syT[buf][l31][(k + 1) * 16 + lh * 8];
                acc0 = MFMA(wf[k], y0, acc0);
                acc1 = MFMA(wf[k + 1], y1, acc1);
            }

            // ===== epilogue: all-register res update =====
            #pragma unroll
            for (int m = 0; m < 8; ++m) {
                const int r0 = 2 * m;
                const int o0 = 32 * wv + 4 * lh + 2 * (m & 1) + 8 * (m >> 1);
                float v0 = acc0[r0] + acc1[r0] + bq[r0] + uplo(rp[s][m]);
                float v1 = acc0[r0 + 1] + acc1[r0 + 1] + bq[r0 + 1] + uphi(rp[s][m]);
                v0 = fmaxf(v0, 0.f);
                v1 = fmaxf(v1, 0.f);
                rp[s][m] = pk2(v0, v1);
                if (blk == 3 && l31 < VV) {
                    out[(((size_t)n * CC + o0) * TT + t0 + s) * VV + l31]     = v0;
                    out[(((size_t)n * CC + o0 + 1) * TT + t0 + s) * VV + l31] = v1;
                }
            }
        }
    }
}

extern "C" void kernel_launch(void* const* d_in, const int* in_sizes, int n_in,
                              void* d_out, int out_size, void* d_ws, size_t ws_size,
                              hipStream_t stream) {
    const float* x  = (const float*)d_in[1];
    const float* A  = (const float*)d_in[2];
    const float* w1 = (const float*)d_in[3];
    const float* b1 = (const float*)d_in[4];
    const float* w2 = (const float*)d_in[5];
    const float* b2 = (const float*)d_in[6];
    const float* w3 = (const float*)d_in[7];
    const float* b3 = (const float*)d_in[8];
    const float* w4 = (const float*)d_in[9];
    const float* b4 = (const float*)d_in[10];
    float* out = (float*)d_out;
    bf16* wp = (bf16*)d_ws;   // 512 KB packed w fragments

    convert_w<<<128, 256, 0, stream>>>(w1, w2, w3, w4, wp);
    ode_fused<<<512, 512, 0, stream>>>(x, A, wp, b1, b2, b3, b4, out);
}